// Round 5
// baseline (323.028 us; speedup 1.0000x reference)
//
#include <hip/hip_runtime.h>
#include <math.h>

#define SEQ    2048
#define EMBED  1024
#define HEADS  16
#define HDIM   64
#define BATCH  4
#define ROWS   (BATCH * SEQ)    // 8192
#define BH     (BATCH * HEADS)  // 64

typedef _Float16 f16;
typedef __attribute__((ext_vector_type(8))) _Float16 f16x8;
typedef __attribute__((ext_vector_type(4))) _Float16 f16x4;
typedef __attribute__((ext_vector_type(4))) float    f32x4;

#define LOG2E_10 0.14426950408889634f   // log2(e)/10

// fast 2^x via the HW transcendental unit
__device__ __forceinline__ float fast_exp2(float x) { return __builtin_amdgcn_exp2f(x); }

// async global->LDS copy, 16B per lane. LDS dest = uniform base + lane*16.
__device__ __forceinline__ void async16(void* l, const void* g) {
    __builtin_amdgcn_global_load_lds(
        (__attribute__((address_space(1))) void*)(uintptr_t)g,
        (__attribute__((address_space(3))) void*)(uint32_t)(uintptr_t)l,
        16, 0, 0);
}

__device__ __forceinline__ f32x4 mfma16(f16x8 a, f16x8 b, f32x4 c) {
    return __builtin_amdgcn_mfma_f32_16x16x32_f16(a, b, c, 0, 0, 0);
}
// K=16 variant: A,B are f16x4; used for PV where P stays register-resident.
__device__ __forceinline__ f32x4 mfma16k16(f16x4 a, f16x4 b, f32x4 c) {
    return __builtin_amdgcn_mfma_f32_16x16x16f16(a, b, c, 0, 0, 0);
}

// ---------------------------------------------------------------------------
// Kernel 0: fp32 -> fp16 convert. x -> xh [8192][1024]; Wq/Wk/Wv -> Wh
// concatenated [3072][1024]. Memory-bound, ~15us.
// ---------------------------------------------------------------------------
#define NX4 (ROWS * EMBED / 4)          // 2097152
#define NW4 (EMBED * EMBED / 4)         // 262144
__global__ __launch_bounds__(256) void cvt_kernel(
    const float* __restrict__ x,
    const float* __restrict__ Wq, const float* __restrict__ Wk,
    const float* __restrict__ Wv,
    f16* __restrict__ xh, f16* __restrict__ Wh)
{
    int i = blockIdx.x * 256 + threadIdx.x;
    const float4* src; f16* dst; int j;
    if (i < NX4)              { src = (const float4*)x;  dst = xh;                j = i; }
    else if (i < NX4 + NW4)   { src = (const float4*)Wq; dst = Wh;                j = i - NX4; }
    else if (i < NX4 + 2*NW4) { src = (const float4*)Wk; dst = Wh + EMBED*EMBED;  j = i - NX4 - NW4; }
    else                      { src = (const float4*)Wv; dst = Wh + 2*EMBED*EMBED;j = i - NX4 - 2*NW4; }
    float4 v = src[j];
    f16x4 h;
    h[0] = (f16)v.x; h[1] = (f16)v.y; h[2] = (f16)v.z; h[3] = (f16)v.w;
    *(f16x4*)(dst + (size_t)j * 4) = h;
}

// ---------------------------------------------------------------------------
// Kernel 1: fused QKV projection GEMM (f16 MFMA, m97 structure, single-buffer
// 2-barrier form -- dbuf measured negative in R3).
// C[8192][3072] = xh @ Wh^T + bias. 128x128 tile, BK=32, global_load_lds w=16.
// Epilogue: Q (PRE-SCALED by log2e/10) -> [bh][s][d] f16; K -> same layout;
// V -> transposed Vt [bh][d][s] f16.  Q-prescale lets stats/out feed MFMA
// output straight into exp2 (saves one VALU op per S element downstream).
// ---------------------------------------------------------------------------
__global__ __launch_bounds__(256) void proj_kernel(
    const f16* __restrict__ A,   // [8192][1024]
    const f16* __restrict__ W,   // [3072][1024]
    const float* __restrict__ bq, const float* __restrict__ bk,
    const float* __restrict__ bv,
    f16* __restrict__ Qh, f16* __restrict__ Kh, f16* __restrict__ Vt)
{
    __shared__ f16 As[128 * 32];   // [row][32k], rows 64B, unpadded (glds layout)
    __shared__ f16 Bs[128 * 32];

    const int t = threadIdx.x, wv = t >> 6, lane = t & 63;
    const int lm = lane & 15, quad = lane >> 4;
    const int r0 = blockIdx.x * 128, c0 = blockIdx.y * 128;
    const int wm = wv & 1, wn = wv >> 1;

    const int srow = wv * 32 + (lane >> 2);
    const int sch  = (lane & 3) * 8;     // f16 units (16B chunks)
    const f16* gA = A + (size_t)(r0 + srow) * EMBED + sch;
    const f16* gB = W + (size_t)(c0 + srow) * EMBED + sch;
    f16* lA = As + wv * 1024;
    f16* lB = Bs + wv * 1024;

    f32x4 acc[4][4];
#pragma unroll
    for (int i = 0; i < 4; ++i)
#pragma unroll
        for (int j = 0; j < 4; ++j) acc[i][j] = (f32x4){0.f, 0.f, 0.f, 0.f};

    for (int kk = 0; kk < EMBED; kk += 32) {
        __syncthreads();
        async16(lA,        gA + kk);
        async16(lA + 512,  gA + 16 * EMBED + kk);
        async16(lB,        gB + kk);
        async16(lB + 512,  gB + 16 * EMBED + kk);
        __syncthreads();

        f16x8 af[4], bf[4];
#pragma unroll
        for (int i = 0; i < 4; ++i)
            af[i] = *(const f16x8*)&As[(wm * 64 + i * 16 + lm) * 32 + quad * 8];
#pragma unroll
        for (int i = 0; i < 4; ++i)
            bf[i] = *(const f16x8*)&Bs[(wn * 64 + i * 16 + lm) * 32 + quad * 8];
#pragma unroll
        for (int mi = 0; mi < 4; ++mi)
#pragma unroll
            for (int ni = 0; ni < 4; ++ni)
                acc[mi][ni] = mfma16(af[mi], bf[ni], acc[mi][ni]);
    }

    const int z = c0 >> 10;              // 0=Q 1=K 2=V (128 | 1024 so no straddle)
    const float* bias = (z == 0) ? bq : (z == 1) ? bk : bv;
    const float osc = (z == 0) ? LOG2E_10 : 1.0f;   // Q pre-scale
#pragma unroll
    for (int ni = 0; ni < 4; ++ni) {
        int col = c0 + wn * 64 + ni * 16 + lm;
        int cz  = col & 1023;
        float bb = bias[cz];
        int h = cz >> 6, d = cz & 63;
#pragma unroll
        for (int mi = 0; mi < 4; ++mi) {
            int rbase = r0 + wm * 64 + mi * 16 + quad * 4;
            int b = rbase >> 11, s = rbase & 2047;   // 4 rows stay in same b
            if (z < 2) {
                f16* O = (z == 0) ? Qh : Kh;
                size_t base = ((size_t)(b * HEADS + h) * SEQ + s) * HDIM + d;
#pragma unroll
                for (int r = 0; r < 4; ++r)
                    O[base + (size_t)r * HDIM] = (f16)((acc[mi][ni][r] + bb) * osc);
            } else {
                f16x4 pk;
#pragma unroll
                for (int r = 0; r < 4; ++r) pk[r] = (f16)(acc[mi][ni][r] + bb);
                *(f16x4*)&Vt[((size_t)(b * HEADS + h) * HDIM + d) * SEQ + s] = pk;
            }
        }
    }
}

// XCD swizzle decode: 1024 blocks, 8 XCDs. d = xcd + 8*(x + 16*ygrp):
// all 16 blocks sharing a bh land on one XCD (hw round-robins wgid % 8).
__device__ __forceinline__ void xcd_decode(int d, int& bh, int& x128) {
    int xcd  = d & 7;
    int r    = d >> 3;
    x128     = (r & 15) * 128;
    bh       = (r >> 4) * 8 + xcd;
}

// ---------------------------------------------------------------------------
// Kernel 2: column stats + V pre-scale.
// colsum[k] = sum_q exp2(S'[q,k])  (S' = prescaled-Q . K = S*log2e/10).
// Then Vt2[bh][d][k] = Vt[bh][d][k] * 1024/colsum[k] -- the softmax
// normalizer depends only on k, so it folds into V and out_kernel never
// touches it.  Block owns 128 k-cols (strip of Vt), XCD-swizzled.
// R2 single-buffer 2-barrier structure; 128B-row tiles chunk-XOR-swizzled.
// ---------------------------------------------------------------------------
__global__ __launch_bounds__(256) void stats_kernel(
    const f16* __restrict__ Qh, const f16* __restrict__ Kh,
    const f16* __restrict__ Vt, f16* __restrict__ Vt2)
{
    __shared__ f16 Ks[128 * 64];   // [kcol][d] rows 128B, chunk-swizzled
    __shared__ f16 Qs[64 * 64];    // [q][d], chunk-swizzled (epilogue: sc[])

    const int t = threadIdx.x, wv = t >> 6, lane = t & 63;
    const int lm = lane & 15, quad = lane >> 4;
    int bh, k0;
    xcd_decode(blockIdx.x, bh, k0);
    const int grow = lane >> 3;
    const int gsw  = ((lane & 7) ^ grow) * 8;
    const int rs   = lm & 7;
    const size_t base = (size_t)bh * SEQ * HDIM;

#pragma unroll
    for (int i = 0; i < 4; ++i) {
        int g = wv * 4 + i;
        async16(Ks + g * 512, Kh + base + (size_t)(k0 + g * 8 + grow) * HDIM + gsw);
    }
    __syncthreads();

    f16x8 kf[2][2];   // [coltile][dstep] -- stays in registers all sweep
#pragma unroll
    for (int ct = 0; ct < 2; ++ct)
#pragma unroll
        for (int ds = 0; ds < 2; ++ds)
            kf[ct][ds] = *(const f16x8*)&Ks[(wv * 32 + ct * 16 + lm) * 64
                                            + (((ds * 4 + quad) ^ rs) << 3)];

    float cs0 = 0.f, cs1 = 0.f;
    for (int q0 = 0; q0 < SEQ; q0 += 64) {
        __syncthreads();
#pragma unroll
        for (int i = 0; i < 2; ++i) {
            int g = wv * 2 + i;
            async16(Qs + g * 512, Qh + base + (size_t)(q0 + g * 8 + grow) * HDIM + gsw);
        }
        __syncthreads();
#pragma unroll
        for (int qt = 0; qt < 4; ++qt) {
            f16x8 a0 = *(const f16x8*)&Qs[(qt * 16 + lm) * 64 + ((quad ^ rs) << 3)];
            f16x8 a1 = *(const f16x8*)&Qs[(qt * 16 + lm) * 64 + (((4 + quad) ^ rs) << 3)];
            f32x4 c0v = (f32x4){0.f, 0.f, 0.f, 0.f};
            f32x4 c1v = (f32x4){0.f, 0.f, 0.f, 0.f};
            c0v = mfma16(a0, kf[0][0], c0v); c0v = mfma16(a1, kf[0][1], c0v);
            c1v = mfma16(a0, kf[1][0], c1v); c1v = mfma16(a1, kf[1][1], c1v);
#pragma unroll
            for (int r = 0; r < 4; ++r) {
                cs0 += fast_exp2(c0v[r]);   // Q pre-scaled: arg ready as-is
                cs1 += fast_exp2(c1v[r]);
            }
        }
    }
    // reduce quad dimension; after butterfly all lanes hold the full sum
    cs0 += __shfl_xor(cs0, 16, 64); cs0 += __shfl_xor(cs0, 32, 64);
    cs1 += __shfl_xor(cs1, 16, 64); cs1 += __shfl_xor(cs1, 32, 64);

    // --- V pre-scale epilogue: Vt2 strip [64 d][128 k] = Vt * 1024/colsum ---
    __syncthreads();                 // Qs dead; reuse as sc[128] broadcast
    float* sc = (float*)Qs;
    if (quad == 0) {
        sc[wv * 32 + lm]      = 1024.0f / cs0;
        sc[wv * 32 + 16 + lm] = 1024.0f / cs1;
    }
    __syncthreads();
    const int row = t >> 2, cb = (t & 3) * 32;
    const f16* src = Vt  + base + (size_t)row * SEQ + k0 + cb;
    f16*       dst = Vt2 + base + (size_t)row * SEQ + k0 + cb;
#pragma unroll
    for (int c = 0; c < 4; ++c) {
        f16x8 v = *(const f16x8*)(src + c * 8);
        f16x8 o;
#pragma unroll
        for (int j = 0; j < 8; ++j)
            o[j] = (f16)((float)v[j] * sc[cb + c * 8 + j]);
        *(f16x8*)(dst + c * 8) = o;
    }
}

// ---------------------------------------------------------------------------
// Kernel 3: out[q,d] = (1/1024) * sum_k exp2(S'[q,k]) * Vt2[d,k].
// Register-P (R4 structure): waves 2x2 over (q-half wq, k-half wk); S^T =
// K.Q'^T C-layout IS the 16x16x16 A-frag layout, so P feeds PV from regs.
// R5 deltas: no lg/Ls at all (normalizer folded into Vt2); Q frags loaded
// DIRECT from global (drops 16KB Q-LDS -> 32KB total -> 4 blocks/CU,
// occupancy ~2x); per-element VALU now just exp2 + cvt.
// ---------------------------------------------------------------------------
__global__ __launch_bounds__(256) void out_kernel(
    const f16* __restrict__ Qh, const f16* __restrict__ Kh,
    const f16* __restrict__ Vt2, float* __restrict__ out)
{
    // LDS: Ks[2][4096] | Vs[2][4096] f16 = 32 KB; epilogue red aliases all.
    __shared__ f16 L[16384];

    const int t = threadIdx.x, wv = t >> 6, lane = t & 63;
    const int lm = lane & 15, quad = lane >> 4;
    const int wq = wv >> 1, wk = wv & 1;
    int bh, q0;
    xcd_decode(blockIdx.x, bh, q0);
    const int b = bh >> 4, h = bh & 15;
    const int grow = lane >> 3;
    const int gsw  = ((lane & 7) ^ grow) * 8;   // swizzled 16B source chunk
    const int rs   = lm & 7;                    // read-side row swizzle key
    const size_t base = (size_t)bh * SEQ * HDIM;   // same stride for Qh/Kh/Vt2

    f16* Ks = L;          // [2][4096]
    f16* Vs = L + 8192;   // [2][4096]

    // Q fragments direct from global (one-time; 64B-contiguous per 4 lanes)
    f16x8 qa[4][2];
#pragma unroll
    for (int qt = 0; qt < 4; ++qt)
#pragma unroll
        for (int ds = 0; ds < 2; ++ds)
            qa[qt][ds] = *(const f16x8*)(Qh + base
                          + (size_t)(q0 + wq * 64 + qt * 16 + lm) * HDIM
                          + ds * 32 + quad * 8);

    // stage K/V tile 0
#pragma unroll
    for (int i = 0; i < 2; ++i) {
        int g = wv * 2 + i;
        async16(Ks + g * 512, Kh  + base + (size_t)(g * 8 + grow) * HDIM + gsw);
        async16(Vs + g * 512, Vt2 + base + (size_t)(g * 8 + grow) * SEQ + gsw);
    }
    __syncthreads();

    f32x4 oacc[4][4];
#pragma unroll
    for (int i = 0; i < 4; ++i)
#pragma unroll
        for (int j = 0; j < 4; ++j) oacc[i][j] = (f32x4){0.f, 0.f, 0.f, 0.f};

    for (int it = 0; it < SEQ / 64; ++it) {
        const int cur = it & 1;
        if (it + 1 < SEQ / 64) {
            const int nxt = cur ^ 1, k0n = (it + 1) * 64;
#pragma unroll
            for (int i = 0; i < 2; ++i) {
                int g = wv * 2 + i;
                async16(Ks + nxt * 4096 + g * 512,
                        Kh + base + (size_t)(k0n + g * 8 + grow) * HDIM + gsw);
                async16(Vs + nxt * 4096 + g * 512,
                        Vt2 + base + (size_t)(g * 8 + grow) * SEQ + k0n + gsw);
            }
        }
        const f16* Kb = Ks + cur * 4096;
        const f16* Vb = Vs + cur * 4096;

#pragma unroll
        for (int ct = 0; ct < 2; ++ct) {
            const int kb = wk * 32 + ct * 16;   // k-local base of sub-tile
            f16x8 kf0 = *(const f16x8*)&Kb[(kb + lm) * 64 + ((quad ^ rs) << 3)];
            f16x8 kf1 = *(const f16x8*)&Kb[(kb + lm) * 64 + (((4 + quad) ^ rs) << 3)];
            const int vch = ((wk * 4 + ct * 2 + (quad >> 1)) ^ rs);
            f16x4 vb[4];
#pragma unroll
            for (int dt = 0; dt < 4; ++dt)
                vb[dt] = *(const f16x4*)&Vb[(dt * 16 + lm) * 64 + vch * 8 + (quad & 1) * 4];
#pragma unroll
            for (int qt = 0; qt < 4; ++qt) {
                f32x4 s4 = (f32x4){0.f, 0.f, 0.f, 0.f};
                s4 = mfma16(kf0, qa[qt][0], s4);
                s4 = mfma16(kf1, qa[qt][1], s4);
                // lane holds S'[q=wq*64+qt*16+lm][k=kb+quad*4+r]: the
                // 16x16x16 A-frag layout. P = exp2(S') straight to regs.
                f16x4 pa;
#pragma unroll
                for (int r = 0; r < 4; ++r)
                    pa[r] = (f16)fast_exp2(s4[r]);
#pragma unroll
                for (int dt = 0; dt < 4; ++dt)
                    oacc[qt][dt] = mfma16k16(pa, vb[dt], oacc[qt][dt]);
            }
        }
        __syncthreads();   // drains stage vmcnt + buffer reuse
    }

    // cross-wk reduction: wk=1 writes partials to LDS (aliases Ks/Vs, dead
    // after the final loop barrier), wk=0 adds + stores.
    float* red = (float*)L;   // [2][64*64] = 32 KB
    if (wk == 1) {
#pragma unroll
        for (int qt = 0; qt < 4; ++qt)
#pragma unroll
            for (int dt = 0; dt < 4; ++dt)
#pragma unroll
                for (int r = 0; r < 4; ++r)
                    red[wq * 4096 + (qt * 16 + quad * 4 + r) * 64 + dt * 16 + lm]
                        = oacc[qt][dt][r];
    }
    __syncthreads();
    if (wk == 0) {
        const float inv1024 = 1.0f / 1024.0f;
#pragma unroll
        for (int qt = 0; qt < 4; ++qt)
#pragma unroll
            for (int dt = 0; dt < 4; ++dt) {
                int col = h * HDIM + dt * 16 + lm;
#pragma unroll
                for (int r = 0; r < 4; ++r) {
                    int ql = qt * 16 + quad * 4 + r;
                    int s  = q0 + wq * 64 + ql;
                    float v = oacc[qt][dt][r]
                            + red[wq * 4096 + ql * 64 + dt * 16 + lm];
                    out[((size_t)b * SEQ + s) * EMBED + col] = v * inv1024;
                }
            }
    }
}

extern "C" void kernel_launch(void* const* d_in, const int* in_sizes, int n_in,
                              void* d_out, int out_size, void* d_ws, size_t ws_size,
                              hipStream_t stream) {
    const float* x  = (const float*)d_in[0];
    const float* Wq = (const float*)d_in[1];
    const float* bq = (const float*)d_in[2];
    const float* Wk = (const float*)d_in[3];
    const float* bk = (const float*)d_in[4];
    const float* Wv = (const float*)d_in[5];
    const float* bv = (const float*)d_in[6];
    float* out = (float*)d_out;

    f16* xh = (f16*)d_ws;                          // 8388608 f16
    f16* Wh = xh + (size_t)ROWS * EMBED;           // 3145728
    f16* Qh = Wh + (size_t)3 * EMBED * EMBED;      // 8388608
    f16* Kh = Qh + (size_t)BH * SEQ * HDIM;        // 8388608
    f16* Vt = Kh + (size_t)BH * SEQ * HDIM;        // 8388608
    // Vt2 (linv-prescaled V) aliases xh: dead after proj, same size.
    // Each graph replay rewrites xh (cvt) before stats re-derives Vt2,
    // and stats itself is idempotent (reads Vt, writes Vt2).
    f16* Vt2 = xh;

    cvt_kernel<<<(NX4 + 3 * NW4) / 256, 256, 0, stream>>>(x, Wq, Wk, Wv, xh, Wh);
    proj_kernel<<<dim3(ROWS / 128, 3 * EMBED / 128), 256, 0, stream>>>(
        xh, Wh, bq, bk, bv, Qh, Kh, Vt);
    stats_kernel<<<dim3(SEQ / 128 * BH), 256, 0, stream>>>(Qh, Kh, Vt, Vt2);
    out_kernel<<<dim3(SEQ / 128 * BH), 256, 0, stream>>>(Qh, Kh, Vt2, out);
}

// Round 6
// 299.340 us; speedup vs baseline: 1.0791x; 1.0791x over previous
//
#include <hip/hip_runtime.h>
#include <math.h>

#define SEQ    2048
#define EMBED  1024
#define HEADS  16
#define HDIM   64
#define BATCH  4
#define ROWS   (BATCH * SEQ)    // 8192
#define BH     (BATCH * HEADS)  // 64
#define NT     (SEQ / 64)       // 32 k-tiles

typedef _Float16 f16;
typedef __attribute__((ext_vector_type(8))) _Float16 f16x8;
typedef __attribute__((ext_vector_type(4))) _Float16 f16x4;
typedef __attribute__((ext_vector_type(4))) float    f32x4;

#define LOG2E_10 0.14426950408889634f   // log2(e)/10

// fast 2^x via the HW transcendental unit
__device__ __forceinline__ float fast_exp2(float x) { return __builtin_amdgcn_exp2f(x); }

// counted waits + raw barrier (T4): memory clobber pins glds/ds ops on both
// sides; s_barrier intrinsic is side-effecting so memory ops don't cross it.
#define WAIT_VM0() asm volatile("s_waitcnt vmcnt(0)" ::: "memory")
#define WAIT_VM2() asm volatile("s_waitcnt vmcnt(2)" ::: "memory")
#define WAIT_VM4() asm volatile("s_waitcnt vmcnt(4)" ::: "memory")
#define WAIT_LGKM0() asm volatile("s_waitcnt lgkmcnt(0)" ::: "memory")
#define BAR() __builtin_amdgcn_s_barrier()

// async global->LDS copy, 16B per lane. LDS dest = uniform base + lane*16.
__device__ __forceinline__ void async16(void* l, const void* g) {
    __builtin_amdgcn_global_load_lds(
        (__attribute__((address_space(1))) void*)(uintptr_t)g,
        (__attribute__((address_space(3))) void*)(uint32_t)(uintptr_t)l,
        16, 0, 0);
}

__device__ __forceinline__ f32x4 mfma16(f16x8 a, f16x8 b, f32x4 c) {
    return __builtin_amdgcn_mfma_f32_16x16x32_f16(a, b, c, 0, 0, 0);
}
// K=16 variant: A,B are f16x4; used for PV where P stays register-resident.
__device__ __forceinline__ f32x4 mfma16k16(f16x4 a, f16x4 b, f32x4 c) {
    return __builtin_amdgcn_mfma_f32_16x16x16f16(a, b, c, 0, 0, 0);
}

// ---------------------------------------------------------------------------
// Kernel 0: fp32 -> fp16 convert. x -> xh [8192][1024]; Wq/Wk/Wv -> Wh
// concatenated [3072][1024]. Memory-bound, ~15us.
// ---------------------------------------------------------------------------
#define NX4 (ROWS * EMBED / 4)          // 2097152
#define NW4 (EMBED * EMBED / 4)         // 262144
__global__ __launch_bounds__(256) void cvt_kernel(
    const float* __restrict__ x,
    const float* __restrict__ Wq, const float* __restrict__ Wk,
    const float* __restrict__ Wv,
    f16* __restrict__ xh, f16* __restrict__ Wh)
{
    int i = blockIdx.x * 256 + threadIdx.x;
    const float4* src; f16* dst; int j;
    if (i < NX4)              { src = (const float4*)x;  dst = xh;                j = i; }
    else if (i < NX4 + NW4)   { src = (const float4*)Wq; dst = Wh;                j = i - NX4; }
    else if (i < NX4 + 2*NW4) { src = (const float4*)Wk; dst = Wh + EMBED*EMBED;  j = i - NX4 - NW4; }
    else                      { src = (const float4*)Wv; dst = Wh + 2*EMBED*EMBED;j = i - NX4 - 2*NW4; }
    float4 v = src[j];
    f16x4 h;
    h[0] = (f16)v.x; h[1] = (f16)v.y; h[2] = (f16)v.z; h[3] = (f16)v.w;
    *(f16x4*)(dst + (size_t)j * 4) = h;
}

// ---------------------------------------------------------------------------
// Kernel 1: fused QKV projection GEMM (f16 MFMA, m97 structure, single-buffer
// 2-barrier form). C[8192][3072] = xh @ Wh^T + bias. 128x128 tile, BK=32.
// Epilogue: Q (PRE-SCALED by log2e/10) -> [bh][s][d]; K -> same; V -> Vt
// transposed [bh][d][s].
// ---------------------------------------------------------------------------
__global__ __launch_bounds__(256) void proj_kernel(
    const f16* __restrict__ A,   // [8192][1024]
    const f16* __restrict__ W,   // [3072][1024]
    const float* __restrict__ bq, const float* __restrict__ bk,
    const float* __restrict__ bv,
    f16* __restrict__ Qh, f16* __restrict__ Kh, f16* __restrict__ Vt)
{
    __shared__ f16 As[128 * 32];   // [row][32k], rows 64B, unpadded (glds layout)
    __shared__ f16 Bs[128 * 32];

    const int t = threadIdx.x, wv = t >> 6, lane = t & 63;
    const int lm = lane & 15, quad = lane >> 4;
    const int r0 = blockIdx.x * 128, c0 = blockIdx.y * 128;
    const int wm = wv & 1, wn = wv >> 1;

    const int srow = wv * 32 + (lane >> 2);
    const int sch  = (lane & 3) * 8;     // f16 units (16B chunks)
    const f16* gA = A + (size_t)(r0 + srow) * EMBED + sch;
    const f16* gB = W + (size_t)(c0 + srow) * EMBED + sch;
    f16* lA = As + wv * 1024;
    f16* lB = Bs + wv * 1024;

    f32x4 acc[4][4];
#pragma unroll
    for (int i = 0; i < 4; ++i)
#pragma unroll
        for (int j = 0; j < 4; ++j) acc[i][j] = (f32x4){0.f, 0.f, 0.f, 0.f};

    for (int kk = 0; kk < EMBED; kk += 32) {
        __syncthreads();
        async16(lA,        gA + kk);
        async16(lA + 512,  gA + 16 * EMBED + kk);
        async16(lB,        gB + kk);
        async16(lB + 512,  gB + 16 * EMBED + kk);
        __syncthreads();

        f16x8 af[4], bf[4];
#pragma unroll
        for (int i = 0; i < 4; ++i)
            af[i] = *(const f16x8*)&As[(wm * 64 + i * 16 + lm) * 32 + quad * 8];
#pragma unroll
        for (int i = 0; i < 4; ++i)
            bf[i] = *(const f16x8*)&Bs[(wn * 64 + i * 16 + lm) * 32 + quad * 8];
#pragma unroll
        for (int mi = 0; mi < 4; ++mi)
#pragma unroll
            for (int ni = 0; ni < 4; ++ni)
                acc[mi][ni] = mfma16(af[mi], bf[ni], acc[mi][ni]);
    }

    const int z = c0 >> 10;              // 0=Q 1=K 2=V (128 | 1024 so no straddle)
    const float* bias = (z == 0) ? bq : (z == 1) ? bk : bv;
    const float osc = (z == 0) ? LOG2E_10 : 1.0f;   // Q pre-scale
#pragma unroll
    for (int ni = 0; ni < 4; ++ni) {
        int col = c0 + wn * 64 + ni * 16 + lm;
        int cz  = col & 1023;
        float bb = bias[cz];
        int h = cz >> 6, d = cz & 63;
#pragma unroll
        for (int mi = 0; mi < 4; ++mi) {
            int rbase = r0 + wm * 64 + mi * 16 + quad * 4;
            int b = rbase >> 11, s = rbase & 2047;   // 4 rows stay in same b
            if (z < 2) {
                f16* O = (z == 0) ? Qh : Kh;
                size_t base = ((size_t)(b * HEADS + h) * SEQ + s) * HDIM + d;
#pragma unroll
                for (int r = 0; r < 4; ++r)
                    O[base + (size_t)r * HDIM] = (f16)((acc[mi][ni][r] + bb) * osc);
            } else {
                f16x4 pk;
#pragma unroll
                for (int r = 0; r < 4; ++r) pk[r] = (f16)(acc[mi][ni][r] + bb);
                *(f16x4*)&Vt[((size_t)(b * HEADS + h) * HDIM + d) * SEQ + s] = pk;
            }
        }
    }
}

// XCD swizzle decode: 1024 blocks, 8 XCDs. d = xcd + 8*(x + 16*ygrp):
// all 16 blocks sharing a bh land on one XCD (hw round-robins wgid % 8).
__device__ __forceinline__ void xcd_decode(int d, int& bh, int& x128) {
    int xcd  = d & 7;
    int r    = d >> 3;
    x128     = (r & 15) * 128;
    bh       = (r >> 4) * 8 + xcd;
}

// ---------------------------------------------------------------------------
// Kernel 2: column stats + V pre-scale.
// colsum[k] = sum_q exp2(S'[q,k]); Vt2[bh][d][k] = Vt * 1024/colsum[k].
// T4 pipeline: Q tiles double-buffered, depth-2 in flight, raw s_barrier +
// counted vmcnt(2) (vmcnt(0) only on the final tile). 128B-row tiles
// chunk-XOR-swizzled via pre-swizzled global source.
// ---------------------------------------------------------------------------
__global__ __launch_bounds__(256) void stats_kernel(
    const f16* __restrict__ Qh, const f16* __restrict__ Kh,
    const f16* __restrict__ Vt, f16* __restrict__ Vt2)
{
    __shared__ f16 Ks[128 * 64];      // 16KB K panel, never overwritten
    __shared__ f16 Qs[2 * 64 * 64];   // 16KB double-buffered Q tiles

    const int t = threadIdx.x, wv = t >> 6, lane = t & 63;
    const int lm = lane & 15, quad = lane >> 4;
    int bh, k0;
    xcd_decode(blockIdx.x, bh, k0);
    const int grow = lane >> 3;
    const int gsw  = ((lane & 7) ^ grow) * 8;
    const int rs   = lm & 7;
    const size_t base = (size_t)bh * SEQ * HDIM;

    // prologue: K panel (4 glds/wave) + Q tiles 0,1 (2 glds/wave each)
#pragma unroll
    for (int i = 0; i < 4; ++i) {
        int g = wv * 4 + i;
        async16(Ks + g * 512, Kh + base + (size_t)(k0 + g * 8 + grow) * HDIM + gsw);
    }
#pragma unroll
    for (int bi = 0; bi < 2; ++bi)
#pragma unroll
        for (int i = 0; i < 2; ++i) {
            int g = wv * 2 + i;
            async16(Qs + bi * 4096 + g * 512,
                    Qh + base + (size_t)(bi * 64 + g * 8 + grow) * HDIM + gsw);
        }
    WAIT_VM4();   // K panel landed (Q0,Q1 still in flight)
    BAR();

    f16x8 kf[2][2];   // [coltile][dstep] -- stays in registers all sweep
#pragma unroll
    for (int ct = 0; ct < 2; ++ct)
#pragma unroll
        for (int ds = 0; ds < 2; ++ds)
            kf[ct][ds] = *(const f16x8*)&Ks[(wv * 32 + ct * 16 + lm) * 64
                                            + (((ds * 4 + quad) ^ rs) << 3)];

    float cs0 = 0.f, cs1 = 0.f;
    for (int it = 0; it < NT; ++it) {
        const int cur = it & 1;
        if (it == NT - 1) WAIT_VM0(); else WAIT_VM2();   // tile it ready
        BAR();
        const f16* Qb = Qs + cur * 4096;
#pragma unroll
        for (int qt = 0; qt < 4; ++qt) {
            f16x8 a0 = *(const f16x8*)&Qb[(qt * 16 + lm) * 64 + ((quad ^ rs) << 3)];
            f16x8 a1 = *(const f16x8*)&Qb[(qt * 16 + lm) * 64 + (((4 + quad) ^ rs) << 3)];
            f32x4 c0v = (f32x4){0.f, 0.f, 0.f, 0.f};
            f32x4 c1v = (f32x4){0.f, 0.f, 0.f, 0.f};
            c0v = mfma16(a0, kf[0][0], c0v); c0v = mfma16(a1, kf[0][1], c0v);
            c1v = mfma16(a0, kf[1][0], c1v); c1v = mfma16(a1, kf[1][1], c1v);
#pragma unroll
            for (int r = 0; r < 4; ++r) {
                cs0 += fast_exp2(c0v[r]);   // Q pre-scaled: arg ready as-is
                cs1 += fast_exp2(c1v[r]);
            }
        }
        WAIT_LGKM0();   // this wave's reads of buf[cur] complete
        BAR();          // all waves done -> safe to overwrite buf[cur]
        if (it + 2 < NT) {
            const int qn = (it + 2) * 64;
#pragma unroll
            for (int i = 0; i < 2; ++i) {
                int g = wv * 2 + i;
                async16(Qs + cur * 4096 + g * 512,
                        Qh + base + (size_t)(qn + g * 8 + grow) * HDIM + gsw);
            }
        }
    }
    // reduce quad dimension; after butterfly all lanes hold the full sum
    cs0 += __shfl_xor(cs0, 16, 64); cs0 += __shfl_xor(cs0, 32, 64);
    cs1 += __shfl_xor(cs1, 16, 64); cs1 += __shfl_xor(cs1, 32, 64);

    // --- V pre-scale epilogue: Vt2 strip [64 d][128 k] = Vt * 1024/colsum ---
    float* sc = (float*)Qs;          // Qs dead after final BAR
    if (quad == 0) {
        sc[wv * 32 + lm]      = 1024.0f / cs0;
        sc[wv * 32 + 16 + lm] = 1024.0f / cs1;
    }
    __syncthreads();
    const int row = t >> 2, cb = (t & 3) * 32;
    const f16* src = Vt  + base + (size_t)row * SEQ + k0 + cb;
    f16*       dst = Vt2 + base + (size_t)row * SEQ + k0 + cb;
#pragma unroll
    for (int c = 0; c < 4; ++c) {
        f16x8 v = *(const f16x8*)(src + c * 8);
        f16x8 o;
#pragma unroll
        for (int j = 0; j < 8; ++j)
            o[j] = (f16)((float)v[j] * sc[cb + c * 8 + j]);
        *(f16x8*)(dst + c * 8) = o;
    }
}

// ---------------------------------------------------------------------------
// Kernel 3: out[q,d] = (1/1024) * sum_k exp2(S'[q,k]) * Vt2[d,k].
// Register-P (R4 structure) + T4 counted-vmcnt pipeline. Q staged through
// the Ks LDS region in the prologue (frags -> regs, then region reused),
// so LDS stays 32KB and VGPR pressure stays low. K/V tiles double-buffered,
// 4 glds/wave/tile, vmcnt(4) steady-state, vmcnt(0) only on the last tile.
// ---------------------------------------------------------------------------
__global__ __launch_bounds__(256) void out_kernel(
    const f16* __restrict__ Qh, const f16* __restrict__ Kh,
    const f16* __restrict__ Vt2, float* __restrict__ out)
{
    // f16 units: Ks[2][4096] @ 0, Vs[2][4096] @ 8192. Q prologue uses
    // [0,8192); epilogue red (float[2][4096]) aliases all 32KB.
    __shared__ f16 L[16384];

    const int t = threadIdx.x, wv = t >> 6, lane = t & 63;
    const int lm = lane & 15, quad = lane >> 4;
    const int wq = wv >> 1, wk = wv & 1;
    int bh, q0;
    xcd_decode(blockIdx.x, bh, q0);
    const int b = bh >> 4, h = bh & 15;
    const int grow = lane >> 3;
    const int gsw  = ((lane & 7) ^ grow) * 8;   // swizzled 16B source chunk
    const int rs   = lm & 7;                    // read-side row swizzle key
    const size_t base = (size_t)bh * SEQ * HDIM;   // same stride for Qh/Kh/Vt2

    // --- prologue: Q[128][64] through LDS -> register fragments ---
#pragma unroll
    for (int i = 0; i < 4; ++i) {
        int g = wv * 4 + i;
        async16(L + g * 512, Qh + base + (size_t)(q0 + g * 8 + grow) * HDIM + gsw);
    }
    WAIT_VM0();
    BAR();
    f16x8 qa[4][2];   // Q fragments (B-operand of S^T), pinned in regs
#pragma unroll
    for (int qt = 0; qt < 4; ++qt)
#pragma unroll
        for (int ds = 0; ds < 2; ++ds)
            qa[qt][ds] = *(const f16x8*)&L[(wq * 64 + qt * 16 + lm) * 64
                                           + (((ds * 4 + quad) ^ rs) << 3)];
    WAIT_LGKM0();   // all Q reads complete before region reuse
    BAR();
    // stage K/V tiles 0,1 (4 glds/wave per tile)
#pragma unroll
    for (int bi = 0; bi < 2; ++bi)
#pragma unroll
        for (int i = 0; i < 2; ++i) {
            int g = wv * 2 + i;
            async16(L + bi * 4096 + g * 512,
                    Kh + base + (size_t)(bi * 64 + g * 8 + grow) * HDIM + gsw);
            async16(L + 8192 + bi * 4096 + g * 512,
                    Vt2 + base + (size_t)(g * 8 + grow) * SEQ + bi * 64 + gsw);
        }

    f32x4 oacc[4][4];
#pragma unroll
    for (int i = 0; i < 4; ++i)
#pragma unroll
        for (int j = 0; j < 4; ++j) oacc[i][j] = (f32x4){0.f, 0.f, 0.f, 0.f};

    for (int it = 0; it < NT; ++it) {
        const int cur = it & 1;
        if (it == NT - 1) WAIT_VM0(); else WAIT_VM4();   // tile it ready
        BAR();
        const f16* Kb = L + cur * 4096;
        const f16* Vb = L + 8192 + cur * 4096;

#pragma unroll
        for (int ct = 0; ct < 2; ++ct) {
            const int kb = wk * 32 + ct * 16;   // k-local base of sub-tile
            f16x8 kf0 = *(const f16x8*)&Kb[(kb + lm) * 64 + ((quad ^ rs) << 3)];
            f16x8 kf1 = *(const f16x8*)&Kb[(kb + lm) * 64 + (((4 + quad) ^ rs) << 3)];
            const int vch = ((wk * 4 + ct * 2 + (quad >> 1)) ^ rs);
            f16x4 vb[4];
#pragma unroll
            for (int dt = 0; dt < 4; ++dt)
                vb[dt] = *(const f16x4*)&Vb[(dt * 16 + lm) * 64 + vch * 8 + (quad & 1) * 4];
#pragma unroll
            for (int qt = 0; qt < 4; ++qt) {
                f32x4 s4 = (f32x4){0.f, 0.f, 0.f, 0.f};
                s4 = mfma16(kf0, qa[qt][0], s4);
                s4 = mfma16(kf1, qa[qt][1], s4);
                // lane holds S'[q=wq*64+qt*16+lm][k=kb+quad*4+r]: the
                // 16x16x16 A-frag layout. P = exp2(S') straight to regs.
                f16x4 pa;
#pragma unroll
                for (int r = 0; r < 4; ++r)
                    pa[r] = (f16)fast_exp2(s4[r]);
#pragma unroll
                for (int dt = 0; dt < 4; ++dt)
                    oacc[qt][dt] = mfma16k16(pa, vb[dt], oacc[qt][dt]);
            }
        }
        WAIT_LGKM0();   // this wave's reads of buf[cur] complete
        BAR();          // all waves done -> safe to overwrite buf[cur]
        if (it + 2 < NT) {
            const int kn = (it + 2) * 64;
#pragma unroll
            for (int i = 0; i < 2; ++i) {
                int g = wv * 2 + i;
                async16(L + cur * 4096 + g * 512,
                        Kh + base + (size_t)(kn + g * 8 + grow) * HDIM + gsw);
                async16(L + 8192 + cur * 4096 + g * 512,
                        Vt2 + base + (size_t)(g * 8 + grow) * SEQ + kn + gsw);
            }
        }
    }

    // cross-wk reduction: wk=1 writes partials to LDS (aliases Ks/Vs, dead
    // after the final loop barrier), wk=0 adds + stores.
    float* red = (float*)L;   // [2][64*64] = 32 KB
    if (wk == 1) {
#pragma unroll
        for (int qt = 0; qt < 4; ++qt)
#pragma unroll
            for (int dt = 0; dt < 4; ++dt)
#pragma unroll
                for (int r = 0; r < 4; ++r)
                    red[wq * 4096 + (qt * 16 + quad * 4 + r) * 64 + dt * 16 + lm]
                        = oacc[qt][dt][r];
    }
    __syncthreads();
    if (wk == 0) {
        const float inv1024 = 1.0f / 1024.0f;
#pragma unroll
        for (int qt = 0; qt < 4; ++qt)
#pragma unroll
            for (int dt = 0; dt < 4; ++dt) {
                int col = h * HDIM + dt * 16 + lm;
#pragma unroll
                for (int r = 0; r < 4; ++r) {
                    int ql = qt * 16 + quad * 4 + r;
                    int s  = q0 + wq * 64 + ql;
                    float v = oacc[qt][dt][r]
                            + red[wq * 4096 + ql * 64 + dt * 16 + lm];
                    out[((size_t)b * SEQ + s) * EMBED + col] = v * inv1024;
                }
            }
    }
}

extern "C" void kernel_launch(void* const* d_in, const int* in_sizes, int n_in,
                              void* d_out, int out_size, void* d_ws, size_t ws_size,
                              hipStream_t stream) {
    const float* x  = (const float*)d_in[0];
    const float* Wq = (const float*)d_in[1];
    const float* bq = (const float*)d_in[2];
    const float* Wk = (const float*)d_in[3];
    const float* bk = (const float*)d_in[4];
    const float* Wv = (const float*)d_in[5];
    const float* bv = (const float*)d_in[6];
    float* out = (float*)d_out;

    f16* xh = (f16*)d_ws;                          // 8388608 f16
    f16* Wh = xh + (size_t)ROWS * EMBED;           // 3145728
    f16* Qh = Wh + (size_t)3 * EMBED * EMBED;      // 8388608
    f16* Kh = Qh + (size_t)BH * SEQ * HDIM;        // 8388608
    f16* Vt = Kh + (size_t)BH * SEQ * HDIM;        // 8388608
    // Vt2 (normalizer-prescaled V) aliases xh: dead after proj, same size.
    f16* Vt2 = xh;

    cvt_kernel<<<(NX4 + 3 * NW4) / 256, 256, 0, stream>>>(x, Wq, Wk, Wv, xh, Wh);
    proj_kernel<<<dim3(ROWS / 128, 3 * EMBED / 128), 256, 0, stream>>>(
        xh, Wh, bq, bk, bv, Qh, Kh, Vt);
    stats_kernel<<<dim3(SEQ / 128 * BH), 256, 0, stream>>>(Qh, Kh, Vt, Vt2);
    out_kernel<<<dim3(SEQ / 128 * BH), 256, 0, stream>>>(Qh, Kh, Vt2, out);
}